// Round 15
// baseline (82.972 us; speedup 1.0000x reference)
//
#include <hip/hip_runtime.h>
#include <math.h>

#define NROWS 262144
#define DIM   256
#define NC    64
#define CD    (NC*DIM)       // 16384
#define NBLK  512            // k_main blocks, 512 rows each

// ws float-offset layout:
//  cent_new [16384]      @ 0
//  s_final  [64]         @ 16384
//  abs_part [256]        @ 16448
//  pair_part[64]         @ 16704
//  s_part   [512*64]     @ 16768
//  partials [512*16384]  @ 49536   (ushort/bf16: 16.8 MB)
#define OFF_CENT   0
#define OFF_SF     16384
#define OFF_ABS    16448
#define OFF_PAIR   16704
#define OFF_SPART  16768
#define OFF_PART   49536

typedef short  bf16x8 __attribute__((ext_vector_type(8)));
typedef float  f32x16 __attribute__((ext_vector_type(16)));

// DPP 64-lane sum: after these 6 adds, lane 63 holds the full sum.
#define DPP_ADD(v, ctrl) \
    ((v) + __int_as_float(__builtin_amdgcn_update_dpp(0, __float_as_int(v), (ctrl), 0xf, 0xf, true)))

__device__ __forceinline__ float dpp_sum64(float v) {
    v = DPP_ADD(v, 0x111);
    v = DPP_ADD(v, 0x112);
    v = DPP_ADD(v, 0x114);
    v = DPP_ADD(v, 0x118);
    v = DPP_ADD(v, 0x142);
    v = DPP_ADD(v, 0x143);
    return v;                // lane 63 = total
}

// pack two f32 -> two bf16 (RNE) in one u32 (lo = first)
__device__ __forceinline__ unsigned int bf16rne2(float lo, float hi) {
    unsigned int ul = __float_as_uint(lo);
    ul = (ul + 0x7FFFu + ((ul >> 16) & 1u)) >> 16;
    unsigned int uh = __float_as_uint(hi);
    uh = (uh + 0x7FFFu + ((uh >> 16) & 1u)) & 0xFFFF0000u;
    return ul | uh;
}
// single f32 -> bf16 ushort (RNE)
__device__ __forceinline__ unsigned short bf16rne1(float v) {
    unsigned int x = __float_as_uint(v);
    return (unsigned short)((x + 0x7FFFu + ((x >> 16) & 1u)) >> 16);
}
__device__ __forceinline__ float bflo(unsigned int u) { return __uint_as_float(u << 16); }
__device__ __forceinline__ float bfhi(unsigned int u) { return __uint_as_float(u & 0xFFFF0000u); }
__device__ __forceinline__ float bfup(unsigned short u) { return __uint_as_float(((unsigned int)u) << 16); }

// MFMA for one 64-row chunk (4 ksteps x 2 class-tiles); A-frags self-built.
__device__ __forceinline__ void do_mfma_chunk(const unsigned short* pb,
                                              const int* tgts, int rbase,
                                              int lane, int d0,
                                              f32x16& a0r, f32x16& a1r)
{
    const int g8  = (lane >> 5) << 3;
    const int cA  = lane & 31;
    const int cB  = 32 + cA;
    const int col = d0 + cA;
    #pragma unroll
    for (int ks = 0; ks < 4; ++ks) {
        const int rA = rbase + ks * 16 + g8;
        const int t0 = tgts[rA+0], t1 = tgts[rA+1], t2 = tgts[rA+2], t3 = tgts[rA+3];
        const int t4 = tgts[rA+4], t5 = tgts[rA+5], t6 = tgts[rA+6], t7 = tgts[rA+7];
        union { unsigned int u[4]; bf16x8 v; } A0, A1, B;
        A0.u[0] = ((t0==cA)?0x3F80u:0u) | (((t1==cA)?0x3F80u:0u) << 16);
        A0.u[1] = ((t2==cA)?0x3F80u:0u) | (((t3==cA)?0x3F80u:0u) << 16);
        A0.u[2] = ((t4==cA)?0x3F80u:0u) | (((t5==cA)?0x3F80u:0u) << 16);
        A0.u[3] = ((t6==cA)?0x3F80u:0u) | (((t7==cA)?0x3F80u:0u) << 16);
        A1.u[0] = ((t0==cB)?0x3F80u:0u) | (((t1==cB)?0x3F80u:0u) << 16);
        A1.u[1] = ((t2==cB)?0x3F80u:0u) | (((t3==cB)?0x3F80u:0u) << 16);
        A1.u[2] = ((t4==cB)?0x3F80u:0u) | (((t5==cB)?0x3F80u:0u) << 16);
        A1.u[3] = ((t6==cB)?0x3F80u:0u) | (((t7==cB)?0x3F80u:0u) << 16);
        const int kr = ks * 16 + g8;
        #pragma unroll
        for (int p = 0; p < 4; ++p) {
            const unsigned int lo = pb[(kr + 2*p    ) * 256 + col];
            const unsigned int hi = pb[(kr + 2*p + 1) * 256 + col];
            B.u[p] = lo | (hi << 16);
        }
        a0r = __builtin_amdgcn_mfma_f32_32x32x16_bf16(A0.v, B.v, a0r, 0, 0, 0);
        a1r = __builtin_amdgcn_mfma_f32_32x32x16_bf16(A1.v, B.v, a1r, 0, 0, 0);
    }
}

// ---- k_main: streaming MFMA scatter-add; classic 2-barrier; LDS-cached cent ----
// (byte-identical compute to R14's proven kernel; only OFF_* values changed)
__global__ __launch_bounds__(512, 4)
void k_main(const float* __restrict__ pred, const float* __restrict__ cent,
            const float* __restrict__ count, const int* __restrict__ tgt,
            float* __restrict__ ws)
{
    __shared__ unsigned short pbf[64 * 256];   // 32 KB bf16 chunk [r][d]
    __shared__ unsigned short cbf[NC * 256];   // 32 KB bf16 centroids [c][d]
    __shared__ int   tgt_s[512];
    __shared__ float inv_s[64];
    __shared__ float vec_s[512];
    __shared__ float sw_s[8][64];

    const int tid  = threadIdx.x;
    const int w    = tid >> 6;        // 8 waves; wave owns dims [32w, 32w+32)
    const int lane = tid & 63;
    const int base = blockIdx.x * 512;

    tgt_s[tid] = tgt[base + tid];
    if (tid < 64) inv_s[tid] = 1.0f / count[tid];
    {
        const float2* c2 = (const float2*)cent;
        unsigned int* cb32 = (unsigned int*)cbf;
        #pragma unroll
        for (int i = 0; i < 16; ++i) {
            const int o = i * 512 + tid;
            const float2 cf = c2[o];
            cb32[o] = bf16rne2(cf.x, cf.y);
        }
    }
    __syncthreads();

    const float4* pred4 = (const float4*)pred;
    const int d0 = w * 32;

    f32x16 acc0 = {};   // classes [0,32)  x dims [d0,d0+32)
    f32x16 acc1 = {};   // classes [32,64) x dims [d0,d0+32)

    #pragma unroll 1
    for (int ch = 0; ch < 8; ++ch) {
        // stage: load 8 rows (row = ch*64 + 8i + w), all loads issued together
        const size_t gr = (size_t)(base + ch * 64) * 64 + lane;
        float4 p0 = pred4[gr + (size_t)( 0 + w) * 64];
        float4 p1 = pred4[gr + (size_t)( 8 + w) * 64];
        float4 p2 = pred4[gr + (size_t)(16 + w) * 64];
        float4 p3 = pred4[gr + (size_t)(24 + w) * 64];
        float4 p4 = pred4[gr + (size_t)(32 + w) * 64];
        float4 p5 = pred4[gr + (size_t)(40 + w) * 64];
        float4 p6 = pred4[gr + (size_t)(48 + w) * 64];
        float4 p7 = pred4[gr + (size_t)(56 + w) * 64];

#define ROW(pp, i)                                                             \
        {                                                                      \
            const int rc = 8*(i) + w;                                          \
            const int r  = ch * 64 + rc;                                       \
            const int c  = tgt_s[r];                                           \
            const float iv = inv_s[c];                                         \
            const uint2 cu = *(const uint2*)&cbf[c * 256 + lane * 4];          \
            const float dx = bflo(cu.x) - pp.x * iv;                           \
            const float dy = bfhi(cu.x) - pp.y * iv;                           \
            const float dz = bflo(cu.y) - pp.z * iv;                           \
            const float dw = bfhi(cu.y) - pp.w * iv;                           \
            float ss = dx*dx + dy*dy + dz*dz + dw*dw;                          \
            ss = dpp_sum64(ss);                                                \
            if (lane == 63) vec_s[r] = sqrtf(ss);                              \
            *(uint2*)&pbf[rc * 256 + lane * 4] =                               \
                make_uint2(bf16rne2(pp.x, pp.y), bf16rne2(pp.z, pp.w));        \
        }
        ROW(p0, 0) ROW(p1, 1) ROW(p2, 2) ROW(p3, 3)
        ROW(p4, 4) ROW(p5, 5) ROW(p6, 6) ROW(p7, 7)
#undef ROW
        __syncthreads();
        do_mfma_chunk(pbf, tgt_s, ch * 64, lane, d0, acc0, acc1);
        __syncthreads();
    }

    // write bf16 partials (C/D layout: col=lane&31, row=(reg&3)+8*(reg>>2)+4*(lane>>5))
    unsigned short* pp = (unsigned short*)(ws + OFF_PART) + (size_t)blockIdx.x * CD;
    const int dim = d0 + (lane & 31);
    #pragma unroll
    for (int reg = 0; reg < 16; ++reg) {
        const int crow = (reg & 3) + 8 * (reg >> 2) + 4 * (lane >> 5);
        pp[(     crow) * 256 + dim] = bf16rne1(acc0[reg]);
        pp[(32 + crow) * 256 + dim] = bf16rne1(acc1[reg]);
    }

    // block-end per-class s reduction (no atomics)
    {
        const float vv = vec_s[w * 64 + lane];
        const int   cc = tgt_s[w * 64 + lane];
        float accs = 0.f;
        for (int k = 0; k < NC; ++k) {
            float sel = (cc == k) ? vv : 0.f;
            sel = dpp_sum64(sel);
            const float tot = __shfl(sel, 63, 64);
            accs += (lane == k) ? tot : 0.f;
        }
        sw_s[w][lane] = accs;
    }
    __syncthreads();
    if (w == 0) {
        float s = 0.f;
        #pragma unroll
        for (int q = 0; q < 8; ++q) s += sw_s[q][lane];
        ws[OFF_SPART + blockIdx.x * 64 + lane] = s;
    }
}

// ---- k_redbuild: FUSED reduce + build.
//  blocks 0..255 : fully reduce 512 bf16 partials for 64 elements each,
//                  write cent_new + abs partial (per block).
//  block 256     : reduce s_part -> s_final.
__global__ __launch_bounds__(256)
void k_redbuild(const float* __restrict__ cent, const float* __restrict__ count,
                const float* __restrict__ dist, float* __restrict__ ws)
{
    const int b = blockIdx.x, t = threadIdx.x;
    __shared__ float red[4][64];
    if (b < 256) {
        const int e  = b * 64 + (t & 63);
        const int ps = t >> 6;                     // 0..3, 128 partials each
        const unsigned short* pp = (const unsigned short*)(ws + OFF_PART) + e;
        float s = 0.f;
        const int pstart = ps * 128;
        #pragma unroll 8
        for (int p = pstart; p < pstart + 128; ++p) s += bfup(pp[(size_t)p * CD]);
        red[ps][t & 63] = s;
        __syncthreads();
        if (t < 64) {
            const float tot = red[0][t] + red[1][t] + red[2][t] + red[3][t];
            const int o = b * 64 + t;
            const int c = o >> 8;                  // constant per block (= b/4)
            const float inv = 1.0f / count[c];
            const float val = cent[o] + tot * inv;
            ws[OFF_CENT + o] = val;
            float a = fabsf(val);
            a = dpp_sum64(a);
            if (t == 63) ws[OFF_ABS + b] = a;
        }
    } else {
        const int c = t & 63, g = t >> 6;          // 4 groups x 128 blocks
        float s = 0.f;
        const int pstart = g * 128;
        #pragma unroll 8
        for (int p = pstart; p < pstart + 128; ++p) s += ws[OFF_SPART + p * 64 + c];
        red[g][c] = s;
        __syncthreads();
        if (t < 64) {
            const float sv = red[0][t] + red[1][t] + red[2][t] + red[3][t];
            ws[OFF_SF + t] = sqrtf(dist[t] + sv) / count[t];
        }
    }
}

// ---- k3: pairwise terms ----
__global__ __launch_bounds__(256)
void k3_pairs(const float* __restrict__ cw, float* __restrict__ ws)
{
    const int i    = blockIdx.x;
    const int tid  = threadIdx.x;
    const int lane = tid & 63;
    const int w    = tid >> 6;
    const float4* c4 = (const float4*)(ws + OFF_CENT);
    const float*  sf = ws + OFF_SF;

    float4 ci = c4[i * 64 + lane];
    float  si = sf[i];
    float acc = 0.f;
    for (int j = w; j < NC; j += 4) {
        if (j == i) continue;
        float4 cj = c4[j * 64 + lane];
        float dx = ci.x - cj.x, dy = ci.y - cj.y;
        float dz = ci.z - cj.z, dw = ci.w - cj.w;
        float ss = dx*dx + dy*dy + dz*dz + dw*dw;
        #pragma unroll
        for (int o = 32; o > 0; o >>= 1) ss += __shfl_xor(ss, o, 64);
        acc += cw[i * NC + j] * (si + sf[j]) / sqrtf(ss);
    }
    __shared__ float wsum[4];
    if (lane == 0) wsum[w] = acc;
    __syncthreads();
    if (tid == 0) ws[OFF_PAIR + i] = wsum[0] + wsum[1] + wsum[2] + wsum[3];
}

// ---- k4: final scalar (256 abs partials + 64 pair partials) ----
__global__ __launch_bounds__(256)
void k4_final(const float* __restrict__ ws, float* __restrict__ out)
{
    const int t = threadIdx.x;   // 256 threads
    float a = ws[OFF_ABS + t];
    float p = (t < 64) ? ws[OFF_PAIR + t] : 0.f;
    #pragma unroll
    for (int o = 32; o > 0; o >>= 1) {
        a += __shfl_xor(a, o, 64);
        p += __shfl_xor(p, o, 64);
    }
    __shared__ float ra[4], rp[4];
    if ((t & 63) == 0) { ra[t >> 6] = a; rp[t >> 6] = p; }
    __syncthreads();
    if (t == 0) {
        float ps = rp[0] + rp[1] + rp[2] + rp[3];
        float as = ra[0] + ra[1] + ra[2] + ra[3];
        out[0] = ps / 64.0f * 63.0f + as * 1e-6f;
    }
}

extern "C" void kernel_launch(void* const* d_in, const int* in_sizes, int n_in,
                              void* d_out, int out_size, void* d_ws, size_t ws_size,
                              hipStream_t stream)
{
    const float* pred  = (const float*)d_in[0];
    const float* cent  = (const float*)d_in[1];
    const float* dist  = (const float*)d_in[2];
    const float* count = (const float*)d_in[3];
    const float* cw    = (const float*)d_in[4];
    const int*   tgt   = (const int*)d_in[5];
    float* ws  = (float*)d_ws;
    float* out = (float*)d_out;

    // no atomics anywhere -> no memset needed
    k_main    <<<NBLK, 512, 0, stream>>>(pred, cent, count, tgt, ws);
    k_redbuild<<<257,  256, 0, stream>>>(cent, count, dist, ws);
    k3_pairs  <<<NC,   256, 0, stream>>>(cw, ws);
    k4_final  <<<1,    256, 0, stream>>>(ws, out);
}